// Round 1
// baseline (3364.058 us; speedup 1.0000x reference)
//
#include <hip/hip_runtime.h>
#include <stdint.h>

typedef _Float16 half8 __attribute__((ext_vector_type(8)));  // 8 fp16 (4 VGPR) MFMA frag
typedef __attribute__((ext_vector_type(4))) float f4;        // fp32x4 accum
typedef __attribute__((ext_vector_type(4))) unsigned int u32x4;
typedef __attribute__((ext_vector_type(2))) unsigned int u32x2;

#define LDA  392   // halves per LDS A row (384 data + 8 pad; 196 words ≡ 4 mod 8 -> 2-way only)
#define EXS  34    // exchange stride (floats)
#define HSTR 56    // sH stride (halves), 112B: 16B-aligned, 28 words ≡ 4 mod 8 -> 2-way only

__device__ __forceinline__ float sigm(float x) { return 1.0f / (1.0f + __expf(-x)); }
__device__ __forceinline__ float tanh_(float x) { return 1.0f - 2.0f / (__expf(2.0f * x) + 1.0f); } // overflow-safe

// ---------------- prologue kernels ----------------

// W_catA[2048][576] = [W_ih | W_hh] fp16 ; also W_ih part of W_catB
extern "C" __global__ void __launch_bounds__(256) k_wcat(
    const float* __restrict__ Wih, const float* __restrict__ Whh,
    _Float16* __restrict__ WA, _Float16* __restrict__ WB)
{
    int idx = blockIdx.x * 256 + threadIdx.x;        // grid 4608 -> exactly 2048*576
    int n = idx / 576, k = idx % 576;
    float v = (k < 64) ? Wih[n * 64 + k] : Whh[n * 512 + (k - 64)];
    _Float16 b = (_Float16)v;
    WA[idx] = b;
    if (k < 64) WB[idx] = b;
}

// W_catB[n][64+k] = W_hh[n][k] + sum_p W_ih[n][p] * W_out[p][k]   (fp32 accum, fp16 store)
extern "C" __global__ void __launch_bounds__(256) k_comb(
    const float* __restrict__ Wih, const float* __restrict__ Whh,
    const float* __restrict__ Wo, _Float16* __restrict__ WB)
{
    int bx = blockIdx.x;                             // grid 4096
    int n = bx >> 1;
    int kh = ((bx & 1) << 8) + threadIdx.x;          // 0..511
    float acc = Whh[n * 512 + kh];
    #pragma unroll 16
    for (int p = 0; p < 64; ++p)
        acc += Wih[n * 64 + p] * Wo[p * 512 + kh];
    WB[n * 576 + 64 + kh] = (_Float16)acc;
}

// Wout fp16, bias0 = b_ih+b_hh, bias1 = bias0 + W_ih@b_out, y_{-1} init (fp32 + fp16 hi/lo, both parities)
extern "C" __global__ void __launch_bounds__(256) k_misc(
    const float* __restrict__ Wo, const float* __restrict__ bih, const float* __restrict__ bhh,
    const float* __restrict__ Wih, const float* __restrict__ bo, const float* __restrict__ x,
    _Float16* __restrict__ WoB, float* __restrict__ b0v, float* __restrict__ b1v,
    float* __restrict__ yf0, float* __restrict__ yf1,
    _Float16* __restrict__ yh0, _Float16* __restrict__ yh1,
    _Float16* __restrict__ yl0, _Float16* __restrict__ yl1)
{
    int idx = blockIdx.x * 256 + threadIdx.x;        // grid 392
    if (idx < 32768) { WoB[idx] = (_Float16)Wo[idx]; return; }
    if (idx < 34816) {
        int n = idx - 32768;
        float b = bih[n] + bhh[n];
        b0v[n] = b;
        float a = b;
        #pragma unroll 16
        for (int p = 0; p < 64; ++p) a += Wih[n * 64 + p] * bo[p];
        b1v[n] = a;
        return;
    }
    if (idx < 100352) {
        int e = idx - 34816;
        int m = e >> 6, nn = e & 63;
        float v = x[m * 2048 + 31 * 64 + nn];        // x[:, -1, :]
        yf0[e] = v; yf1[e] = v;
        _Float16 hi = (_Float16)v;
        _Float16 lo = (_Float16)(v - (float)hi);
        yh0[e] = hi; yh1[e] = hi;
        yl0[e] = lo; yl1[e] = lo;
    }
}

// h0 = z @ Wproj^T + b_proj ; c0 = h0 ; h stored fp16 hi/lo
extern "C" __global__ void __launch_bounds__(256) k_h0(
    const float* __restrict__ z, const float* __restrict__ Wp, const float* __restrict__ bp,
    float* __restrict__ cst, _Float16* __restrict__ hh0, _Float16* __restrict__ hl0)
{
    int bx = blockIdx.x;                             // grid 2048
    int m = bx >> 1;
    int n = ((bx & 1) << 8) + threadIdx.x;
    float acc = bp[n];
    const f4* zr = (const f4*)&z[m * 128];           // block-uniform (scalar loads)
    const f4* wr = (const f4*)&Wp[n * 128];
    #pragma unroll 8
    for (int p = 0; p < 32; ++p) {
        f4 zv = zr[p], wv = wr[p];
        acc += zv[0]*wv[0] + zv[1]*wv[1] + zv[2]*wv[2] + zv[3]*wv[3];
    }
    cst[m * 512 + n] = acc;
    _Float16 hi = (_Float16)acc;
    hh0[m * 512 + n] = hi;
    hl0[m * 512 + n] = (_Float16)(acc - (float)hi);
}

// ---------------- per-step kernel ----------------
// grid 512 = 32 mt x 16 s: block (mt, s): rows m0..m0+32, h-cols j0..j0+32 (all 4 gate quadrants)
// 2 blocks/CU resident (launch_bounds (256,2)) -> 8 waves/CU so staging/barrier latency of one
// block is covered by the other block's MFMA/VALU phases.
// A layout (K=1152): [y_hi(0..64) | y_lo(64..128) | h_hi(128..640) | h_lo(640..1152)]
// B col for global-k g: g<64 ? g : (g<640 ? g-64 : g-576)   (lo-half reuses the same fp16 B)
// t in [0,128]; t==128 -> resolution of y_127 only.
extern "C" __global__ void __launch_bounds__(256, 2) k_step(
    int t,
    const _Float16* __restrict__ Wcat,         // [2048][576] fp16 (A or B variant)
    const float* __restrict__ bias,            // [2048]
    const _Float16* __restrict__ Wout,         // [64][512] fp16
    const float* __restrict__ bout,            // [64]
    const _Float16* __restrict__ hh_in, const _Float16* __restrict__ hl_in,  // [1024][512]
    _Float16* __restrict__ hh_out, _Float16* __restrict__ hl_out,
    float* __restrict__ cst,                   // [1024][512] fp32 (in-place)
    const float* __restrict__ yf_in, float* __restrict__ yf_out,             // [1024][64]
    const _Float16* __restrict__ yh_in, _Float16* __restrict__ yh_out,
    const _Float16* __restrict__ yl_in, _Float16* __restrict__ yl_out,
    const float* __restrict__ dl_in, float* __restrict__ dl_out,             // [16][1024][64]
    float* __restrict__ out)                   // [1024][128][64]
{
    __shared__ __align__(16) unsigned char smem[32256];
    _Float16* sA  = (_Float16*)smem;                             // A chunk: 32 x LDA = 25,088 B
    float*    sEx = (float*)smem;                                // overlay: [4][32][EXS] = 17,408 B
    _Float16* sHh = (_Float16*)(smem + 25088);                   // [32][HSTR] = 3,584 B
    _Float16* sHl = (_Float16*)(smem + 28672);                   // [32][HSTR]

    const int tid = threadIdx.x;
    const int bx  = blockIdx.x;
    const int mt  = bx >> 4, s = bx & 15;
    const int m0  = mt * 32, j0 = s * 32;

    // ---- resolve y_{t-1} = y_{t-2} + b_out + sum_s Delta_{t-1,s} (2 rows per block) ----
    if (t >= 1 && tid < 32) {
        int row = m0 + s * 2 + (tid >> 4);
        int c4  = (tid & 15) * 4;
        f4 a = *(const f4*)&yf_in[row * 64 + c4];
        a += *(const f4*)&bout[c4];
        #pragma unroll
        for (int sp = 0; sp < 16; ++sp)
            a += *(const f4*)&dl_in[sp * 65536 + row * 64 + c4];
        *(f4*)&yf_out[row * 64 + c4] = a;
        *(f4*)&out[row * 8192 + (t - 1) * 64 + c4] = a;
        _Float16 hi4[4], lo4[4];
        #pragma unroll
        for (int x = 0; x < 4; ++x) {
            hi4[x] = (_Float16)a[x];
            lo4[x] = (_Float16)(a[x] - (float)hi4[x]);
        }
        *(u32x2*)&yh_out[row * 64 + c4] = *(u32x2*)hi4;
        *(u32x2*)&yl_out[row * 64 + c4] = *(u32x2*)lo4;
    }
    if (t >= 128) return;

    const int wv = tid >> 6, lane = tid & 63, l15 = lane & 15, quad = lane >> 4;
    const int quad8 = quad * 8;

    f4 zero = {0.0f, 0.0f, 0.0f, 0.0f};
    f4 acc[2][2];
    #pragma unroll
    for (int a = 0; a < 2; ++a) { acc[a][0] = zero; acc[a][1] = zero; }

    const int brow0 = (wv * 512 + j0 + l15) * 576;
    const int brow1 = (wv * 512 + j0 + 16 + l15) * 576;

    // ---- 3 staged chunks of K=384 over the split-A (K=1152) gates GEMM ----
    #pragma unroll
    for (int ch = 0; ch < 3; ++ch) {
        if (ch) __syncthreads();                     // previous chunk's MFMAs done
        #pragma unroll
        for (int it = 0; it < 6; ++it) {             // 6*256*16B = 32 rows x 384 halves
            int i4 = it * 256 + tid;
            int r = i4 / 48, cc = (i4 % 48) * 8;
            int g = ch * 384 + cc;
            const _Float16* src;
            if (g < 64)       src = &yh_in[(m0 + r) * 64 + g];
            else if (g < 128) src = &yl_in[(m0 + r) * 64 + (g - 64)];
            else if (g < 640) src = &hh_in[(m0 + r) * 512 + (g - 128)];
            else              src = &hl_in[(m0 + r) * 512 + (g - 640)];
            *(u32x4*)&sA[r * LDA + cc] = *(const u32x4*)src;
        }
        __syncthreads();
        #pragma unroll
        for (int kc = 0; kc < 12; ++kc) {
            const int g0  = ch * 384 + kc * 32;
            const int bc0 = (g0 < 64) ? g0 : ((g0 < 640) ? g0 - 64 : g0 - 576);
            int kq = kc * 32 + quad8;
            int bq = bc0 + quad8;
            half8 a0 = *(const half8*)&sA[(l15     ) * LDA + kq];
            half8 a1 = *(const half8*)&sA[(l15 + 16) * LDA + kq];
            half8 b0 = *(const half8*)&Wcat[brow0 + bq];
            half8 b1 = *(const half8*)&Wcat[brow1 + bq];
            acc[0][0] = __builtin_amdgcn_mfma_f32_16x16x32_f16(a0, b0, acc[0][0], 0, 0, 0);
            acc[1][0] = __builtin_amdgcn_mfma_f32_16x16x32_f16(a1, b0, acc[1][0], 0, 0, 0);
            acc[0][1] = __builtin_amdgcn_mfma_f32_16x16x32_f16(a0, b1, acc[0][1], 0, 0, 0);
            acc[1][1] = __builtin_amdgcn_mfma_f32_16x16x32_f16(a1, b1, acc[1][1], 0, 0, 0);
        }
    }
    __syncthreads();                                  // sA dead -> overlay exchange

    // ---- gate exchange: wave wv = quadrant wv (i,f,g,o). D layout: col=lane&15, row=quad*4+reg ----
    #pragma unroll
    for (int a = 0; a < 2; ++a)
        #pragma unroll
        for (int b = 0; b < 2; ++b)
            #pragma unroll
            for (int r = 0; r < 4; ++r)
                sEx[(wv * 32 + a * 16 + quad * 4 + r) * EXS + b * 16 + l15] = acc[a][b][r];
    __syncthreads();

    // ---- LSTM cell update: thread -> row m, 4 h-cols ----
    {
        int m = tid >> 3, jb = (tid & 7) * 4;
        int jcol = j0 + jb;
        int crow = (m0 + m) * 512 + jcol;
        f4 c0 = *(const f4*)&cst[crow];
        _Float16 hi4[4], lo4[4];
        #pragma unroll
        for (int x = 0; x < 4; ++x) {
            float gi = sEx[(0 * 32 + m) * EXS + jb + x] + bias[       jcol + x];
            float gf = sEx[(1 * 32 + m) * EXS + jb + x] + bias[ 512 + jcol + x];
            float gg = sEx[(2 * 32 + m) * EXS + jb + x] + bias[1024 + jcol + x];
            float go = sEx[(3 * 32 + m) * EXS + jb + x] + bias[1536 + jcol + x];
            float iv = sigm(gi), fv = sigm(gf), gv = tanh_(gg), ov = sigm(go);
            float cn = fv * c0[x] + iv * gv;
            float hn = ov * tanh_(cn);
            c0[x] = cn;
            _Float16 hi = (_Float16)hn;
            hi4[x] = hi;
            lo4[x] = (_Float16)(hn - (float)hi);
        }
        *(f4*)&cst[crow] = c0;
        *(u32x2*)&hh_out[crow]       = *(u32x2*)hi4;
        *(u32x2*)&hl_out[crow]       = *(u32x2*)lo4;
        *(u32x2*)&sHh[m * HSTR + jb] = *(u32x2*)hi4;
        *(u32x2*)&sHl[m * HSTR + jb] = *(u32x2*)lo4;
    }
    __syncthreads();

    // ---- Delta partial: dl_out[s] = (h_hi+h_lo)(strip) @ Wout^T, K=32 per m-tile ----
    {
        half8 bw = *(const half8*)&Wout[(wv * 16 + l15) * 512 + j0 + quad8];
        f4 d[2];
        d[0] = zero; d[1] = zero;
        #pragma unroll
        for (int a = 0; a < 2; ++a) {
            half8 ahh = *(const half8*)&sHh[(a * 16 + l15) * HSTR + quad8];
            half8 ahl = *(const half8*)&sHl[(a * 16 + l15) * HSTR + quad8];
            d[a] = __builtin_amdgcn_mfma_f32_16x16x32_f16(ahh, bw, d[a], 0, 0, 0);
            d[a] = __builtin_amdgcn_mfma_f32_16x16x32_f16(ahl, bw, d[a], 0, 0, 0);
        }
        #pragma unroll
        for (int a = 0; a < 2; ++a)
            #pragma unroll
            for (int r = 0; r < 4; ++r)
                dl_out[s * 65536 + (m0 + a * 16 + quad * 4 + r) * 64 + wv * 16 + l15] = d[a][r];
    }
}

// ---------------- host ----------------
extern "C" void kernel_launch(void* const* d_in, const int* in_sizes, int n_in,
                              void* d_out, int out_size, void* d_ws, size_t ws_size,
                              hipStream_t stream)
{
    const float* z   = (const float*)d_in[0];
    const float* x   = (const float*)d_in[1];
    const float* Wih = (const float*)d_in[2];
    const float* Whh = (const float*)d_in[3];
    const float* bih = (const float*)d_in[4];
    const float* bhh = (const float*)d_in[5];
    const float* Wp  = (const float*)d_in[6];
    const float* bp  = (const float*)d_in[7];
    const float* Wo  = (const float*)d_in[8];
    const float* bo  = (const float*)d_in[9];

    char* w = (char*)d_ws;
    _Float16* WA  = (_Float16*)w; w += 2359296;   // [2048][576] fp16
    _Float16* WB  = (_Float16*)w; w += 2359296;
    _Float16* WoB = (_Float16*)w; w += 65536;     // [64][512] fp16
    float* b0v = (float*)w; w += 8192;
    float* b1v = (float*)w; w += 8192;
    _Float16* hh[2];
    hh[0] = (_Float16*)w; w += 1048576;
    hh[1] = (_Float16*)w; w += 1048576;
    _Float16* hl[2];
    hl[0] = (_Float16*)w; w += 1048576;
    hl[1] = (_Float16*)w; w += 1048576;
    float* cst = (float*)w; w += 2097152;
    float* yf[2];
    yf[0] = (float*)w; w += 262144;
    yf[1] = (float*)w; w += 262144;
    _Float16* yh[2];
    yh[0] = (_Float16*)w; w += 131072;
    yh[1] = (_Float16*)w; w += 131072;
    _Float16* yl[2];
    yl[0] = (_Float16*)w; w += 131072;
    yl[1] = (_Float16*)w; w += 131072;
    float* dl[2];
    dl[0] = (float*)w; w += 4194304;              // [16][1024][64] fp32
    dl[1] = (float*)w; w += 4194304;
    float* out = (float*)d_out;

    k_wcat<<<4608, 256, 0, stream>>>(Wih, Whh, WA, WB);
    k_comb<<<4096, 256, 0, stream>>>(Wih, Whh, Wo, WB);
    k_misc<<<392, 256, 0, stream>>>(Wo, bih, bhh, Wih, bo, x, WoB, b0v, b1v,
                                    yf[0], yf[1], yh[0], yh[1], yl[0], yl[1]);
    k_h0<<<2048, 256, 0, stream>>>(z, Wp, bp, cst, hh[0], hl[0]);

    for (int t = 0; t <= 128; ++t) {
        k_step<<<512, 256, 0, stream>>>(t,
            (t == 0) ? WA : WB, (t == 0) ? b0v : b1v,
            WoB, bo,
            hh[t & 1], hl[t & 1], hh[(t + 1) & 1], hl[(t + 1) & 1],
            cst,
            yf[t & 1], yf[(t + 1) & 1],
            yh[t & 1], yh[(t + 1) & 1],
            yl[t & 1], yl[(t + 1) & 1],
            dl[(t + 1) & 1], dl[t & 1],
            out);
    }
}

// Round 2
// 1993.630 us; speedup vs baseline: 1.6874x; 1.6874x over previous
//
#include <hip/hip_runtime.h>
#include <stdint.h>

typedef _Float16 half8 __attribute__((ext_vector_type(8)));  // 8 fp16 (4 VGPR) MFMA frag
typedef __attribute__((ext_vector_type(4))) float f4;        // fp32x4 accum
typedef __attribute__((ext_vector_type(4))) unsigned int u32x4;
typedef __attribute__((ext_vector_type(2))) unsigned int u32x2;

#define LDAH 200   // halves per LDS A row (192 data + 8 pad; 100 words ≡ 4 mod 8 -> conflict-free, 16B aligned)
#define EXS  34    // exchange stride (floats)
#define HSTR 40    // sH stride (halves), 80B: 16B-aligned, 20 words ≡ 4 mod 8 -> 2-way only

__device__ __forceinline__ float sigm(float x) { return 1.0f / (1.0f + __expf(-x)); }
__device__ __forceinline__ float tanh_(float x) { return 1.0f - 2.0f / (__expf(2.0f * x) + 1.0f); } // overflow-safe

// ---------------- prologue kernels ----------------

// W_catA[2048][576] = [W_ih | W_hh] fp16 ; also W_ih part of W_catB
extern "C" __global__ void __launch_bounds__(256) k_wcat(
    const float* __restrict__ Wih, const float* __restrict__ Whh,
    _Float16* __restrict__ WA, _Float16* __restrict__ WB)
{
    int idx = blockIdx.x * 256 + threadIdx.x;        // grid 4608 -> exactly 2048*576
    int n = idx / 576, k = idx % 576;
    float v = (k < 64) ? Wih[n * 64 + k] : Whh[n * 512 + (k - 64)];
    _Float16 b = (_Float16)v;
    WA[idx] = b;
    if (k < 64) WB[idx] = b;
}

// W_catB[n][64+k] = W_hh[n][k] + sum_p W_ih[n][p] * W_out[p][k]   (fp32 accum, fp16 store)
extern "C" __global__ void __launch_bounds__(256) k_comb(
    const float* __restrict__ Wih, const float* __restrict__ Whh,
    const float* __restrict__ Wo, _Float16* __restrict__ WB)
{
    int bx = blockIdx.x;                             // grid 4096
    int n = bx >> 1;
    int kh = ((bx & 1) << 8) + threadIdx.x;          // 0..511
    float acc = Whh[n * 512 + kh];
    #pragma unroll 16
    for (int p = 0; p < 64; ++p)
        acc += Wih[n * 64 + p] * Wo[p * 512 + kh];
    WB[n * 576 + 64 + kh] = (_Float16)acc;
}

// Wout fp16, bias0 = b_ih+b_hh, bias1 = bias0 + W_ih@b_out, y_{-1} init (fp32 + fp16 hi/lo, both parities)
extern "C" __global__ void __launch_bounds__(256) k_misc(
    const float* __restrict__ Wo, const float* __restrict__ bih, const float* __restrict__ bhh,
    const float* __restrict__ Wih, const float* __restrict__ bo, const float* __restrict__ x,
    _Float16* __restrict__ WoB, float* __restrict__ b0v, float* __restrict__ b1v,
    float* __restrict__ yf0, float* __restrict__ yf1,
    _Float16* __restrict__ yh0, _Float16* __restrict__ yh1,
    _Float16* __restrict__ yl0, _Float16* __restrict__ yl1)
{
    int idx = blockIdx.x * 256 + threadIdx.x;        // grid 392
    if (idx < 32768) { WoB[idx] = (_Float16)Wo[idx]; return; }
    if (idx < 34816) {
        int n = idx - 32768;
        float b = bih[n] + bhh[n];
        b0v[n] = b;
        float a = b;
        #pragma unroll 16
        for (int p = 0; p < 64; ++p) a += Wih[n * 64 + p] * bo[p];
        b1v[n] = a;
        return;
    }
    if (idx < 100352) {
        int e = idx - 34816;
        int m = e >> 6, nn = e & 63;
        float v = x[m * 2048 + 31 * 64 + nn];        // x[:, -1, :]
        yf0[e] = v; yf1[e] = v;
        _Float16 hi = (_Float16)v;
        _Float16 lo = (_Float16)(v - (float)hi);
        yh0[e] = hi; yh1[e] = hi;
        yl0[e] = lo; yl1[e] = lo;
    }
}

// h0 = z @ Wproj^T + b_proj ; c0 = h0 ; h stored fp16 hi/lo
extern "C" __global__ void __launch_bounds__(256) k_h0(
    const float* __restrict__ z, const float* __restrict__ Wp, const float* __restrict__ bp,
    float* __restrict__ cst, _Float16* __restrict__ hh0, _Float16* __restrict__ hl0)
{
    int bx = blockIdx.x;                             // grid 2048
    int m = bx >> 1;
    int n = ((bx & 1) << 8) + threadIdx.x;
    float acc = bp[n];
    const f4* zr = (const f4*)&z[m * 128];           // block-uniform (scalar loads)
    const f4* wr = (const f4*)&Wp[n * 128];
    #pragma unroll 8
    for (int p = 0; p < 32; ++p) {
        f4 zv = zr[p], wv = wr[p];
        acc += zv[0]*wv[0] + zv[1]*wv[1] + zv[2]*wv[2] + zv[3]*wv[3];
    }
    cst[m * 512 + n] = acc;
    _Float16 hi = (_Float16)acc;
    hh0[m * 512 + n] = hi;
    hl0[m * 512 + n] = (_Float16)(acc - (float)hi);
}

// ---------------- per-step kernel ----------------
// grid 256 = 16 mt x 16 s: block (mt, s): rows m0..m0+64, h-cols j0..j0+32 (all 4 gate quadrants)
// GEMM: K=576 B-cols, each B fragment used for BOTH hi-A and lo-A MFMAs (B traffic halved vs split-K).
// A staged as two LDS streams: sAh (hi fp16) + sAl (lo fp16), 3 chunks x 192 B-cols.
// hi src for B-col c: c<64 ? yh[c] : hh[c-64]; lo src likewise with yl/hl.
// T14 async staging: next chunk's loads issued to regs before current chunk's MFMA phase.
// t in [0,128]; t==128 -> resolution of y_127 only.
extern "C" __global__ void __launch_bounds__(256, 1) k_step(
    int t,
    const _Float16* __restrict__ Wcat,         // [2048][576] fp16 (A or B variant)
    const float* __restrict__ bias,            // [2048]
    const _Float16* __restrict__ Wout,         // [64][512] fp16
    const float* __restrict__ bout,            // [64]
    const _Float16* __restrict__ hh_in, const _Float16* __restrict__ hl_in,  // [1024][512]
    _Float16* __restrict__ hh_out, _Float16* __restrict__ hl_out,
    float* __restrict__ cst,                   // [1024][512] fp32 (in-place)
    const float* __restrict__ yf_in, float* __restrict__ yf_out,             // [1024][64]
    const _Float16* __restrict__ yh_in, _Float16* __restrict__ yh_out,
    const _Float16* __restrict__ yl_in, _Float16* __restrict__ yl_out,
    const float* __restrict__ dl_in, float* __restrict__ dl_out,             // [16][1024][64]
    float* __restrict__ out)                   // [1024][128][64]
{
    __shared__ __align__(16) unsigned char smem[61440];
    _Float16* sAh = (_Float16*)smem;                             // [64][LDAH] = 25,600 B
    _Float16* sAl = (_Float16*)(smem + 25600);                   // [64][LDAH] = 25,600 B
    float*    sEx = (float*)smem;                                // overlay: [4][64][EXS] = 34,816 B
    _Float16* sHh = (_Float16*)(smem + 51200);                   // [64][HSTR] = 5,120 B
    _Float16* sHl = (_Float16*)(smem + 56320);                   // [64][HSTR]

    const int tid = threadIdx.x;
    const int bx  = blockIdx.x;
    const int mt  = bx >> 4, s = bx & 15;
    const int m0  = mt * 64, j0 = s * 32;

    // ---- resolve y_{t-1} = y_{t-2} + b_out + sum_s Delta_{t-1,s} (4 rows per block) ----
    if (t >= 1 && tid < 64) {
        int row = m0 + s * 4 + (tid >> 4);
        int c4  = (tid & 15) * 4;
        f4 a = *(const f4*)&yf_in[row * 64 + c4];
        a += *(const f4*)&bout[c4];
        #pragma unroll
        for (int sp = 0; sp < 16; ++sp)
            a += *(const f4*)&dl_in[sp * 65536 + row * 64 + c4];
        *(f4*)&yf_out[row * 64 + c4] = a;
        *(f4*)&out[row * 8192 + (t - 1) * 64 + c4] = a;
        _Float16 hi4[4], lo4[4];
        #pragma unroll
        for (int x = 0; x < 4; ++x) {
            hi4[x] = (_Float16)a[x];
            lo4[x] = (_Float16)(a[x] - (float)hi4[x]);
        }
        *(u32x2*)&yh_out[row * 64 + c4] = *(u32x2*)hi4;
        *(u32x2*)&yl_out[row * 64 + c4] = *(u32x2*)lo4;
    }
    if (t >= 128) return;

    const int wv = tid >> 6, lane = tid & 63, l15 = lane & 15, quad = lane >> 4;
    const int quad8 = quad * 8;

    f4 zero = {0.0f, 0.0f, 0.0f, 0.0f};
    f4 acc[4][2];
    #pragma unroll
    for (int a = 0; a < 4; ++a) { acc[a][0] = zero; acc[a][1] = zero; }

    const int brow0 = (wv * 512 + j0 + l15) * 576;
    const int brow1 = (wv * 512 + j0 + 16 + l15) * 576;

    // per-thread staging coordinates (fixed across chunks): 6 x 16B covers 64 rows x 192 halves
    int rr[6], cc6[6];
    #pragma unroll
    for (int it = 0; it < 6; ++it) {
        int i4 = it * 256 + tid;
        rr[it]  = i4 / 24;
        cc6[it] = (i4 % 24) * 8;
    }

    // ---- prologue: stage chunk 0 (B-cols 0..191: y part + h[0..127]) ----
    #pragma unroll
    for (int it = 0; it < 6; ++it) {
        int r = rr[it], cc = cc6[it];
        const _Float16 *sh, *sl;
        if (cc < 64) { sh = &yh_in[(m0 + r) * 64 + cc];        sl = &yl_in[(m0 + r) * 64 + cc]; }
        else         { sh = &hh_in[(m0 + r) * 512 + (cc - 64)]; sl = &hl_in[(m0 + r) * 512 + (cc - 64)]; }
        *(u32x4*)&sAh[r * LDAH + cc] = *(const u32x4*)sh;
        *(u32x4*)&sAl[r * LDAH + cc] = *(const u32x4*)sl;
    }

    // ---- 3 chunks of 192 B-cols; B loaded once, feeds hi AND lo MFMAs ----
    u32x4 regH[6], regL[6];
    #pragma unroll
    for (int ch = 0; ch < 3; ++ch) {
        // B prefetch for this chunk (12 loads, L2-hot)
        half8 bv0[6], bv1[6];
        #pragma unroll
        for (int kc = 0; kc < 6; ++kc) {
            int bq = ch * 192 + kc * 32 + quad8;
            bv0[kc] = *(const half8*)&Wcat[brow0 + bq];
            bv1[kc] = *(const half8*)&Wcat[brow1 + bq];
        }
        // T14: issue next chunk's staging loads now; latency hides under MFMA phase
        if (ch < 2) {
            #pragma unroll
            for (int it = 0; it < 6; ++it) {
                int c = (ch + 1) * 192 + cc6[it] - 64;   // >= 128: pure h stream
                regH[it] = *(const u32x4*)&hh_in[(m0 + rr[it]) * 512 + c];
                regL[it] = *(const u32x4*)&hl_in[(m0 + rr[it]) * 512 + c];
            }
        }
        __syncthreads();                                 // this chunk's LDS writes visible
        #pragma unroll
        for (int kc = 0; kc < 6; ++kc) {
            int kq = kc * 32 + quad8;
            half8 ah0 = *(const half8*)&sAh[(l15     ) * LDAH + kq];
            half8 ah1 = *(const half8*)&sAh[(l15 + 16) * LDAH + kq];
            half8 ah2 = *(const half8*)&sAh[(l15 + 32) * LDAH + kq];
            half8 ah3 = *(const half8*)&sAh[(l15 + 48) * LDAH + kq];
            half8 al0 = *(const half8*)&sAl[(l15     ) * LDAH + kq];
            half8 al1 = *(const half8*)&sAl[(l15 + 16) * LDAH + kq];
            half8 al2 = *(const half8*)&sAl[(l15 + 32) * LDAH + kq];
            half8 al3 = *(const half8*)&sAl[(l15 + 48) * LDAH + kq];
            acc[0][0] = __builtin_amdgcn_mfma_f32_16x16x32_f16(ah0, bv0[kc], acc[0][0], 0, 0, 0);
            acc[1][0] = __builtin_amdgcn_mfma_f32_16x16x32_f16(ah1, bv0[kc], acc[1][0], 0, 0, 0);
            acc[2][0] = __builtin_amdgcn_mfma_f32_16x16x32_f16(ah2, bv0[kc], acc[2][0], 0, 0, 0);
            acc[3][0] = __builtin_amdgcn_mfma_f32_16x16x32_f16(ah3, bv0[kc], acc[3][0], 0, 0, 0);
            acc[0][1] = __builtin_amdgcn_mfma_f32_16x16x32_f16(ah0, bv1[kc], acc[0][1], 0, 0, 0);
            acc[1][1] = __builtin_amdgcn_mfma_f32_16x16x32_f16(ah1, bv1[kc], acc[1][1], 0, 0, 0);
            acc[2][1] = __builtin_amdgcn_mfma_f32_16x16x32_f16(ah2, bv1[kc], acc[2][1], 0, 0, 0);
            acc[3][1] = __builtin_amdgcn_mfma_f32_16x16x32_f16(ah3, bv1[kc], acc[3][1], 0, 0, 0);
            acc[0][0] = __builtin_amdgcn_mfma_f32_16x16x32_f16(al0, bv0[kc], acc[0][0], 0, 0, 0);
            acc[1][0] = __builtin_amdgcn_mfma_f32_16x16x32_f16(al1, bv0[kc], acc[1][0], 0, 0, 0);
            acc[2][0] = __builtin_amdgcn_mfma_f32_16x16x32_f16(al2, bv0[kc], acc[2][0], 0, 0, 0);
            acc[3][0] = __builtin_amdgcn_mfma_f32_16x16x32_f16(al3, bv0[kc], acc[3][0], 0, 0, 0);
            acc[0][1] = __builtin_amdgcn_mfma_f32_16x16x32_f16(al0, bv1[kc], acc[0][1], 0, 0, 0);
            acc[1][1] = __builtin_amdgcn_mfma_f32_16x16x32_f16(al1, bv1[kc], acc[1][1], 0, 0, 0);
            acc[2][1] = __builtin_amdgcn_mfma_f32_16x16x32_f16(al2, bv1[kc], acc[2][1], 0, 0, 0);
            acc[3][1] = __builtin_amdgcn_mfma_f32_16x16x32_f16(al3, bv1[kc], acc[3][1], 0, 0, 0);
        }
        if (ch < 2) {
            __syncthreads();                             // all reads of sA done
            #pragma unroll
            for (int it = 0; it < 6; ++it) {             // write-late half of T14 split
                *(u32x4*)&sAh[rr[it] * LDAH + cc6[it]] = regH[it];
                *(u32x4*)&sAl[rr[it] * LDAH + cc6[it]] = regL[it];
            }
        }
    }
    __syncthreads();                                  // sA dead -> overlay exchange

    // ---- gate exchange: wave wv = quadrant wv (i,f,g,o). D layout: col=lane&15, row=quad*4+reg ----
    #pragma unroll
    for (int a = 0; a < 4; ++a)
        #pragma unroll
        for (int b = 0; b < 2; ++b)
            #pragma unroll
            for (int r = 0; r < 4; ++r)
                sEx[(wv * 64 + a * 16 + quad * 4 + r) * EXS + b * 16 + l15] = acc[a][b][r];
    __syncthreads();

    // ---- LSTM cell update: thread -> row m, 8 h-cols ----
    {
        int m = tid >> 2, jb = (tid & 3) * 8;
        int jcol = j0 + jb;
        int crow = (m0 + m) * 512 + jcol;
        f4 c0 = *(const f4*)&cst[crow];
        f4 c1 = *(const f4*)&cst[crow + 4];
        _Float16 hi8[8], lo8[8];
        #pragma unroll
        for (int x = 0; x < 8; ++x) {
            float gi = sEx[(0 * 64 + m) * EXS + jb + x] + bias[       jcol + x];
            float gf = sEx[(1 * 64 + m) * EXS + jb + x] + bias[ 512 + jcol + x];
            float gg = sEx[(2 * 64 + m) * EXS + jb + x] + bias[1024 + jcol + x];
            float go = sEx[(3 * 64 + m) * EXS + jb + x] + bias[1536 + jcol + x];
            float iv = sigm(gi), fv = sigm(gf), gv = tanh_(gg), ov = sigm(go);
            float cold = (x < 4) ? c0[x] : c1[x - 4];
            float cn = fv * cold + iv * gv;
            float hn = ov * tanh_(cn);
            if (x < 4) c0[x] = cn; else c1[x - 4] = cn;
            _Float16 hi = (_Float16)hn;
            hi8[x] = hi;
            lo8[x] = (_Float16)(hn - (float)hi);
        }
        *(f4*)&cst[crow]     = c0;
        *(f4*)&cst[crow + 4] = c1;
        *(u32x4*)&hh_out[crow]       = *(u32x4*)hi8;
        *(u32x4*)&hl_out[crow]       = *(u32x4*)lo8;
        *(u32x4*)&sHh[m * HSTR + jb] = *(u32x4*)hi8;
        *(u32x4*)&sHl[m * HSTR + jb] = *(u32x4*)lo8;
    }
    __syncthreads();

    // ---- Delta partial: dl_out[s] = (h_hi+h_lo)(strip) @ Wout^T, K=32 per m-tile ----
    {
        half8 bw = *(const half8*)&Wout[(wv * 16 + l15) * 512 + j0 + quad8];
        f4 d[4];
        #pragma unroll
        for (int a = 0; a < 4; ++a) d[a] = zero;
        #pragma unroll
        for (int a = 0; a < 4; ++a) {
            half8 ahh = *(const half8*)&sHh[(a * 16 + l15) * HSTR + quad8];
            half8 ahl = *(const half8*)&sHl[(a * 16 + l15) * HSTR + quad8];
            d[a] = __builtin_amdgcn_mfma_f32_16x16x32_f16(ahh, bw, d[a], 0, 0, 0);
            d[a] = __builtin_amdgcn_mfma_f32_16x16x32_f16(ahl, bw, d[a], 0, 0, 0);
        }
        #pragma unroll
        for (int a = 0; a < 4; ++a)
            #pragma unroll
            for (int r = 0; r < 4; ++r)
                dl_out[s * 65536 + (m0 + a * 16 + quad * 4 + r) * 64 + wv * 16 + l15] = d[a][r];
    }
}

// ---------------- host ----------------
extern "C" void kernel_launch(void* const* d_in, const int* in_sizes, int n_in,
                              void* d_out, int out_size, void* d_ws, size_t ws_size,
                              hipStream_t stream)
{
    const float* z   = (const float*)d_in[0];
    const float* x   = (const float*)d_in[1];
    const float* Wih = (const float*)d_in[2];
    const float* Whh = (const float*)d_in[3];
    const float* bih = (const float*)d_in[4];
    const float* bhh = (const float*)d_in[5];
    const float* Wp  = (const float*)d_in[6];
    const float* bp  = (const float*)d_in[7];
    const float* Wo  = (const float*)d_in[8];
    const float* bo  = (const float*)d_in[9];

    char* w = (char*)d_ws;
    _Float16* WA  = (_Float16*)w; w += 2359296;   // [2048][576] fp16
    _Float16* WB  = (_Float16*)w; w += 2359296;
    _Float16* WoB = (_Float16*)w; w += 65536;     // [64][512] fp16
    float* b0v = (float*)w; w += 8192;
    float* b1v = (float*)w; w += 8192;
    _Float16* hh[2];
    hh[0] = (_Float16*)w; w += 1048576;
    hh[1] = (_Float16*)w; w += 1048576;
    _Float16* hl[2];
    hl[0] = (_Float16*)w; w += 1048576;
    hl[1] = (_Float16*)w; w += 1048576;
    float* cst = (float*)w; w += 2097152;
    float* yf[2];
    yf[0] = (float*)w; w += 262144;
    yf[1] = (float*)w; w += 262144;
    _Float16* yh[2];
    yh[0] = (_Float16*)w; w += 131072;
    yh[1] = (_Float16*)w; w += 131072;
    _Float16* yl[2];
    yl[0] = (_Float16*)w; w += 131072;
    yl[1] = (_Float16*)w; w += 131072;
    float* dl[2];
    dl[0] = (float*)w; w += 4194304;              // [16][1024][64] fp32
    dl[1] = (float*)w; w += 4194304;
    float* out = (float*)d_out;

    k_wcat<<<4608, 256, 0, stream>>>(Wih, Whh, WA, WB);
    k_comb<<<4096, 256, 0, stream>>>(Wih, Whh, Wo, WB);
    k_misc<<<392, 256, 0, stream>>>(Wo, bih, bhh, Wih, bo, x, WoB, b0v, b1v,
                                    yf[0], yf[1], yh[0], yh[1], yl[0], yl[1]);
    k_h0<<<2048, 256, 0, stream>>>(z, Wp, bp, cst, hh[0], hl[0]);

    for (int t = 0; t <= 128; ++t) {
        k_step<<<256, 256, 0, stream>>>(t,
            (t == 0) ? WA : WB, (t == 0) ? b0v : b1v,
            WoB, bo,
            hh[t & 1], hl[t & 1], hh[(t + 1) & 1], hl[(t + 1) & 1],
            cst,
            yf[t & 1], yf[(t + 1) & 1],
            yh[t & 1], yh[(t + 1) & 1],
            yl[t & 1], yl[(t + 1) & 1],
            dl[(t + 1) & 1], dl[t & 1],
            out);
    }
}